// Round 14
// baseline (5507.543 us; speedup 1.0000x reference)
//
#include <hip/hip_runtime.h>
#include <hip/hip_bf16.h>

#define LSEQ 1024

typedef __attribute__((ext_vector_type(8))) short short8;
typedef __attribute__((ext_vector_type(4))) float f32x4;
typedef __attribute__((ext_vector_type(4))) unsigned short us4;

static __device__ __forceinline__ short f2bf(float f) {
    unsigned u = __builtin_bit_cast(unsigned, f);
    u += 0x7fffu + ((u >> 16) & 1u);
    return (short)(u >> 16);
}
static __device__ __forceinline__ float bf2f(unsigned short s) {
    unsigned u = ((unsigned)s) << 16;
    return __builtin_bit_cast(float, u);
}
static __device__ __forceinline__ float sigm(float x) { return __fdividef(1.f, 1.f + __expf(-x)); }
static __device__ __forceinline__ float tanh2(float g) { return 1.f - 2.f * __fdividef(1.f, 1.f + __expf(g)); }

static __device__ __forceinline__ void st64g(unsigned long long* p, unsigned long long v) { __hip_atomic_store(p, v, __ATOMIC_RELAXED, __HIP_MEMORY_SCOPE_AGENT); }
static __device__ __forceinline__ unsigned long long ld64g(const unsigned long long* p) { return __hip_atomic_load(p, __ATOMIC_RELAXED, __HIP_MEMORY_SCOPE_AGENT); }

// ============ PHASE 1: Gx[t] = x_t @ Wx + b  (no recurrence, no flags) ============
// R14: PLAIN cacheable stores (R13's nontemporal bypassed L2/L3 -> rec
// streamed 199KB/step from HBM = the 4.7us/step). chunk=64 keeps ringbf at
// 12.4MB = L3-resident. Visibility to phase 2 via kernel-launch boundary.
extern "C" __global__ void __launch_bounds__(512)
gx_kernel(const float* __restrict__ x,
          const float* __restrict__ Wi, const float* __restrict__ bi,
          const float* __restrict__ Wf, const float* __restrict__ bf,
          const float* __restrict__ Wie, const float* __restrict__ bie,
          const float* __restrict__ Wfe, const float* __restrict__ bfe,
          const float* __restrict__ Wz, const float* __restrict__ bz,
          const float* __restrict__ Wo, const float* __restrict__ bo,
          const float* __restrict__ Wd, const float* __restrict__ bdp,
          unsigned short* __restrict__ ringbf, int t0, int spb)
{
    const int tid  = threadIdx.x;
    const int w    = tid >> 6;
    const int lane = tid & 63;
    const int l16  = lane & 15;
    const int lhi  = lane >> 4;

    const int p  = blockIdx.x & 15;
    const int sl = blockIdx.x >> 4;      // t-slice 0..7
    const int g  = p & 3;
    const int qt = p >> 2;
    const int base_ct = qt * 24 + w * 3;
    const int nt = (qt == 3 && w == 7) ? 4 : 3;

    short8 wx[4][8];
    f32x4 bias[4];
    #pragma unroll
    for (int i = 0; i < 4; ++i) {
        if (i < nt) {
            const int ct = base_ct + i;
            if (ct == 96) {
                const float bv = (l16 == 0) ? bdp[0] : 0.f;
                bias[i] = f32x4{bv, bv, bv, bv};
                #pragma unroll
                for (int kk = 0; kk < 8; ++kk) {
                    short8 f;
                    #pragma unroll
                    for (int e = 0; e < 8; ++e)
                        f[e] = (l16 == 0) ? f2bf(Wd[kk * 32 + lhi * 8 + e]) : (short)0;
                    wx[i][kk] = f;
                }
            } else {
                const int gt = ct >> 4, jtg = ct & 15;
                const float* Wg; const float* bg;
                switch (gt) {
                    case 0: Wg = Wi;  bg = bi;  break;
                    case 1: Wg = Wf;  bg = bf;  break;
                    case 2: Wg = Wie; bg = bie; break;
                    case 3: Wg = Wfe; bg = bfe; break;
                    case 4: Wg = Wz;  bg = bz;  break;
                    default: Wg = Wo; bg = bo;  break;
                }
                const int col = jtg * 16 + l16;
                const float bv = bg[col];
                bias[i] = f32x4{bv, bv, bv, bv};
                #pragma unroll
                for (int kk = 0; kk < 8; ++kk) {
                    short8 f;
                    #pragma unroll
                    for (int e = 0; e < 8; ++e)
                        f[e] = f2bf(Wg[(kk * 32 + lhi * 8 + e) * 256 + col]);
                    wx[i][kk] = f;
                }
            }
        }
    }

    const size_t xb = (size_t)(g * 16 + l16) * LSEQ;
    const int tb = t0 + sl * spb;
    for (int ti = 0; ti < spb; ++ti) {
        const int t = tb + ti;
        const float* xp = x + (xb + t) * 256;
        short8 af[8];
        #pragma unroll
        for (int kk = 0; kk < 8; ++kk) {
            const f32x4 a  = *(const f32x4*)(xp + kk * 32 + lhi * 8);
            const f32x4 b2 = *(const f32x4*)(xp + kk * 32 + lhi * 8 + 4);
            short8 f;
            #pragma unroll
            for (int e = 0; e < 4; ++e) { f[e] = f2bf(a[e]); f[4 + e] = f2bf(b2[e]); }
            af[kk] = f;
        }
        f32x4 acc[4];
        #pragma unroll
        for (int i = 0; i < 4; ++i)
            if (i < nt) acc[i] = bias[i];
        #pragma unroll
        for (int kk = 0; kk < 8; ++kk) {
            #pragma unroll
            for (int i = 0; i < 4; ++i)
                if (i < nt)
                    acc[i] = __builtin_amdgcn_mfma_f32_16x16x32_bf16(af[kk], wx[i][kk], acc[i], 0, 0, 0);
        }
        #pragma unroll
        for (int i = 0; i < 4; ++i) {
            if (i < nt) {
                us4 o;
                #pragma unroll
                for (int e = 0; e < 4; ++e) o[e] = (unsigned short)f2bf(acc[i][e]);
                us4* pp = (us4*)&ringbf[(((size_t)(t - t0) * 4 + g) * 97 + base_ct + i) * 256 + lane * 4];
                *pp = o;   // plain cacheable store -> lands in L2/L3
            }
        }
    }
}

// ============ PHASE 2: recurrence over [t0, t1). Gx via plain (cached) loads. ============
// h-exchange: R10-verbatim self-validating 8B records (agent atomics).
extern "C" __global__ void __launch_bounds__(512)
__attribute__((amdgpu_waves_per_eu(2, 2)))
rec_kernel(const float* __restrict__ td,
           const float* __restrict__ Wi, const float* __restrict__ Wf,
           const float* __restrict__ Wie, const float* __restrict__ Wfe,
           const float* __restrict__ Wz, const float* __restrict__ Wo,
           const float* __restrict__ Wd, const float* __restrict__ betap,
           float* __restrict__ out, char* __restrict__ hbuf,
           const unsigned short* __restrict__ ringbf, char* __restrict__ stbuf,
           int t0, int t1)
{
    const int tid  = threadIdx.x;
    const int w    = tid >> 6;
    const int lane = tid & 63;
    const int l16  = lane & 15;
    const int lhi  = lane >> 4;

    const int g = blockIdx.x >> 2;
    const int c = blockIdx.x & 3;

    __shared__ float g_lds[24][17][18];
    __shared__ __align__(16) unsigned short h_lds[2 * 16 * 256];
    __shared__ float dvals[16];
    __shared__ float wd_lds[256];

    if (tid < 256) wd_lds[tid] = Wd[256 + tid];

    char* myst = stbuf + (size_t)blockIdx.x * 32768;
    if (t0 == 0) {
        #pragma unroll
        for (int i = 0; i < 4; ++i) ((unsigned long long*)h_lds)[tid + i * 512] = 0ull;
    } else {
        unsigned long long* dz = (unsigned long long*)((char*)h_lds + (t0 & 1) * 8192);
        const unsigned long long* sz = (const unsigned long long*)myst;
        dz[tid] = sz[tid];
        dz[tid + 512] = sz[tid + 512];
    }

    const float beta = betap[0];

    // resident gate weights (h-part rows 256..511): 3 tiles/wave, 96 VGPR
    short8 wfrag[3][8];
    #pragma unroll
    for (int i = 0; i < 3; ++i) {
        const int T = w * 3 + i, gt = T >> 2, jt = T & 3;
        const float* Wg;
        switch (gt) {
            case 0: Wg = Wi;  break;
            case 1: Wg = Wf;  break;
            case 2: Wg = Wie; break;
            case 3: Wg = Wfe; break;
            case 4: Wg = Wz;  break;
            default: Wg = Wo; break;
        }
        const int col = c * 64 + jt * 16 + l16;
        #pragma unroll
        for (int kk = 0; kk < 8; ++kk) {
            short8 f;
            #pragma unroll
            for (int e = 0; e < 8; ++e)
                f[e] = f2bf(Wg[(256 + kk * 32 + lhi * 8 + e) * 256 + col]);
            wfrag[i][kk] = f;
        }
    }

    const int urow = tid >> 5;
    const int up   = tid & 31;
    float cC[2], ceS[2], h2[2];
    if (t0 == 0) {
        cC[0] = cC[1] = ceS[0] = ceS[1] = h2[0] = h2[1] = 0.f;
    } else {
        const float* fs = (const float*)(myst + 8192) + tid * 6;
        cC[0] = fs[0]; cC[1] = fs[1]; ceS[0] = fs[2]; ceS[1] = fs[3];
        h2[0] = fs[4]; h2[1] = fs[5];
    }

    int myct[3];
    #pragma unroll
    for (int i = 0; i < 3; ++i) {
        const int T = w * 3 + i;
        myct[i] = (T >> 2) * 16 + c * 4 + (T & 3);
    }

    us4 gxr[3];
    unsigned short gxd = 0;
    auto load_gx = [&](int tl) {
        #pragma unroll
        for (int i = 0; i < 3; ++i)
            gxr[i] = *(const us4*)&ringbf[(((size_t)tl * 4 + g) * 97 + myct[i]) * 256 + lane * 4];
        if (w == 0)
            gxd = ringbf[(((size_t)tl * 4 + g) * 97 + 96) * 256 + (l16 >> 2) * 64 + (l16 & 3)];
    };
    load_gx(0);
    __syncthreads();

    for (int t = t0; t < t1; ++t) {
        const int zone_cur = (t & 1) * 8192;
        const int zone_nxt = ((t + 1) & 1) * 8192;

        // ---------- phase G ----------
        short8 hf[8];
        #pragma unroll
        for (int kk = 0; kk < 8; ++kk) {
            const int bo = zone_cur + l16 * 512 + ((kk * 64 + lhi * 16) ^ ((l16 & 7) << 4));
            hf[kk] = *(const short8*)((const char*)h_lds + bo);
        }
        f32x4 acc[3];
        #pragma unroll
        for (int i = 0; i < 3; ++i)
            acc[i] = f32x4{bf2f(gxr[i][0]), bf2f(gxr[i][1]), bf2f(gxr[i][2]), bf2f(gxr[i][3])};
        #pragma unroll
        for (int kk = 0; kk < 8; ++kk) {
            #pragma unroll
            for (int i = 0; i < 3; ++i)
                acc[i] = __builtin_amdgcn_mfma_f32_16x16x32_bf16(hf[kk], wfrag[i][kk], acc[i], 0, 0, 0);
        }
        #pragma unroll
        for (int i = 0; i < 3; ++i) {
            const int T = w * 3 + i, gt = T >> 2;
            #pragma unroll
            for (int q = 0; q < 4; ++q) {
                float v = acc[i][q];
                v = (gt == 4) ? tanh2(v) : sigm(v);
                g_lds[T][lhi * 4 + q][l16] = v;
            }
        }
        if (w == 0) {   // delta head via VALU: row=l16, k-slice=lhi
            float part = 0.f;
            #pragma unroll
            for (int kb = 0; kb < 8; ++kb) {
                const int bo = zone_cur + l16 * 512 + (((lhi * 64 + kb * 8) * 2) ^ ((l16 & 7) << 4));
                const short8 hv = *(const short8*)((const char*)h_lds + bo);
                #pragma unroll
                for (int e = 0; e < 8; ++e)
                    part += bf2f((unsigned short)hv[e]) * wd_lds[lhi * 64 + kb * 8 + e];
            }
            part += __shfl_xor(part, 16);
            part += __shfl_xor(part, 32);
            const float gd = part + bf2f(gxd);
            const float bg_ = beta * gd;
            const float sp  = fmaxf(bg_, 0.f) + __logf(1.f + __expf(-fabsf(bg_)));
            if (lane < 16) dvals[l16] = __fdividef(sp, beta);
        }
        __syncthreads();   // bar1: gates+dvals ready; gxr consumed

        if (t + 1 < t1) load_gx(t + 1 - t0);   // plain loads, L2/L3-hot

        // ---------- phase U ----------
        {
            *(float2*)(out + ((size_t)(g * 16 + urow) * LSEQ + t) * 256 + c * 64 + up * 2)
                = make_float2(h2[0], h2[1]);

            const int jtl = up >> 3;
            const int cc2 = (up & 7) * 2;
            const float2 iv  = *(const float2*)&g_lds[0 * 4 + jtl][urow][cc2];
            const float2 fv  = *(const float2*)&g_lds[1 * 4 + jtl][urow][cc2];
            const float2 iev = *(const float2*)&g_lds[2 * 4 + jtl][urow][cc2];
            const float2 fev = *(const float2*)&g_lds[3 * 4 + jtl][urow][cc2];
            const float2 zv  = *(const float2*)&g_lds[4 * 4 + jtl][urow][cc2];
            const float2 ov  = *(const float2*)&g_lds[5 * 4 + jtl][urow][cc2];
            const float dn = dvals[urow];

            const float cs0 = fv.x * cC[0] + iv.x * zv.x;
            const float cs1 = fv.y * cC[1] + iv.y * zv.y;
            const float ce0 = fev.x * ceS[0] + iev.x * zv.x;
            const float ce1 = fev.y * ceS[1] + iev.y * zv.y;

            if (t + 1 < LSEQ) {
                const float dtv = td[(size_t)(g * 16 + urow) * LSEQ + (t + 1)];
                const float e   = __expf(-dn * dtv);
                const float cn0 = cs0 + (ce0 - cs0) * e;
                const float cn1 = cs1 + (ce1 - cs1) * e;
                const float hv0 = ov.x * tanh2(2.f * cn0);
                const float hv1 = ov.y * tanh2(2.f * cn1);
                cC[0] = cn0; cC[1] = cn1;
                ceS[0] = ce0; ceS[1] = ce1;
                h2[0] = hv0; h2[1] = hv1;
                const unsigned short b0 = (unsigned short)f2bf(hv0);
                const unsigned short b1 = (unsigned short)f2bf(hv1);
                const unsigned long long rec =
                      (unsigned long long)((t + 1) & 0xffff)
                    | ((unsigned long long)b0 << 16)
                    | ((unsigned long long)b1 << 32);
                char* sb = hbuf + ((size_t)((((t + 1) & 1) * 4 + g) * 4 + c)) * 4096;
                st64g((unsigned long long*)(sb + (urow * 32 + up) * 8), rec);
                const unsigned pk = (unsigned)b0 | ((unsigned)b1 << 16);
                const int lin = c * 128 + up * 4;
                *(unsigned*)((char*)h_lds + zone_nxt + urow * 512 + (lin ^ ((urow & 7) << 4))) = pk;
            } else {
                float* so = out + (size_t)64 * LSEQ * 256 + (size_t)(g * 16 + urow) * 769;
                const int jj = c * 64 + up * 2;
                so[jj]           = ov.x; so[jj + 1]       = ov.y;
                so[256 + jj]     = cs0;  so[256 + jj + 1] = cs1;
                so[512 + jj]     = ce0;  so[512 + jj + 1] = ce1;
                if (c == 0 && up == 0) so[768] = dn;
            }
        }

        // ---------- phase P: fetch peer slices by polling records ----------
        if (t + 1 < LSEQ) {
            if (w >= 1 && w <= 3) {
                const int c2 = (c + w) & 3;
                const unsigned long long seqlo = (unsigned long long)((t + 1) & 0xffff);
                const char* sb = hbuf + ((size_t)((((t + 1) & 1) * 4 + g) * 4 + c2)) * 4096;
                unsigned long long rv[8];
                #pragma unroll
                for (int m = 0; m < 8; ++m)
                    rv[m] = ld64g((const unsigned long long*)(sb + (lane * 8 + m) * 8));
                while (true) {
                    bool bad = false;
                    #pragma unroll
                    for (int m = 0; m < 8; ++m)
                        if ((rv[m] & 0xffffull) != seqlo) bad = true;
                    if (!__any(bad)) break;
                    #pragma unroll
                    for (int m = 0; m < 8; ++m)
                        if ((rv[m] & 0xffffull) != seqlo)
                            rv[m] = ld64g((const unsigned long long*)(sb + (lane * 8 + m) * 8));
                }
                #pragma unroll
                for (int m = 0; m < 8; ++m) {
                    const int idx = lane * 8 + m;
                    const int row = idx >> 5;
                    const int rcc = idx & 31;
                    const unsigned val = (unsigned)(rv[m] >> 16);
                    const int lin = c2 * 128 + rcc * 4;
                    *(unsigned*)((char*)h_lds + zone_nxt + row * 512
                                 + (lin ^ ((row & 7) << 4))) = val;
                }
            }
        }
        __syncthreads();   // bar3: h(t+1) fully in LDS
    }

    // chunk-boundary state save
    if (t1 < LSEQ) {
        unsigned long long* dz = (unsigned long long*)myst;
        const unsigned long long* sz = (const unsigned long long*)((char*)h_lds + (t1 & 1) * 8192);
        dz[tid] = sz[tid];
        dz[tid + 512] = sz[tid + 512];
        float* fs = (float*)(myst + 8192) + tid * 6;
        fs[0] = cC[0]; fs[1] = cC[1]; fs[2] = ceS[0]; fs[3] = ceS[1];
        fs[4] = h2[0]; fs[5] = h2[1];
    }
}

extern "C" void kernel_launch(void* const* d_in, const int* in_sizes, int n_in,
                              void* d_out, int out_size, void* d_ws, size_t ws_size,
                              hipStream_t stream) {
    const float* x   = (const float*)d_in[0];
    const float* td  = (const float*)d_in[1];
    const float* Wi  = (const float*)d_in[2];
    const float* bi  = (const float*)d_in[3];
    const float* Wf  = (const float*)d_in[4];
    const float* bf  = (const float*)d_in[5];
    const float* Wie = (const float*)d_in[6];
    const float* bie = (const float*)d_in[7];
    const float* Wfe = (const float*)d_in[8];
    const float* bfe = (const float*)d_in[9];
    const float* Wz  = (const float*)d_in[10];
    const float* bz  = (const float*)d_in[11];
    const float* Wo  = (const float*)d_in[12];
    const float* bo  = (const float*)d_in[13];
    const float* Wd  = (const float*)d_in[14];
    const float* bd  = (const float*)d_in[15];
    const float* be  = (const float*)d_in[16];

    char* hbuf  = (char*)d_ws;                       // 128 KB records (memset)
    char* stbuf = (char*)d_ws + 131072;              // 512 KB chunk state
    unsigned short* ringbf = (unsigned short*)((char*)d_ws + 655360);

    const size_t perstep = (size_t)4 * 97 * 256 * 2; // 198656 B bf16 Gx per step
    // chunk=64 -> ringbf 12.4 MB: L3-resident (the R13 failure was chunk=1024
    // -> 203 MB ringbf streamed from HBM at 199 KB/step on the serial path)
    int chunk = 64;
    while (chunk > 16 && ws_size < 655360 + (size_t)chunk * perstep) chunk >>= 1;

    hipMemsetAsync(d_ws, 0, 131072, stream);         // replay safety: stale seqs
    for (int t0 = 0; t0 < LSEQ; t0 += chunk) {
        hipLaunchKernelGGL(gx_kernel, dim3(128), dim3(512), 0, stream,
                           x, Wi, bi, Wf, bf, Wie, bie, Wfe, bfe, Wz, bz, Wo, bo,
                           Wd, bd, ringbf, t0, chunk >> 3);
        hipLaunchKernelGGL(rec_kernel, dim3(16), dim3(512), 0, stream,
                           td, Wi, Wf, Wie, Wfe, Wz, Wo, Wd, be,
                           (float*)d_out, hbuf, ringbf, stbuf, t0, t0 + chunk);
    }
}